// Round 10
// baseline (7601.693 us; speedup 1.0000x reference)
//
#include <hip/hip_runtime.h>
#include <stdint.h>

// Binarized MLP. Layer 1 bit-exactly emulates a chunk-16 SSE-class einsum dot:
// 4 SSE lanes, ASCENDING 4-strided accumulation (lane j adds elements
// j, 4+j, 8+j, 12+j per 16-chunk, chunks ascending), horizontal sum
// (v0+v1)+(v2+v3). This is numpy's SSE einsum sum-of-products tree
// (old hand-written SSE path; also the universal-intrinsics path with
// ascending muladd chain). Products are exactly +/-x_i (STE weights are
// exactly +/-1 in f32), so only the add order matters. Layers 2/3 are
// exact small-integer popcount arithmetic (order-independent in f32).

#define BATCH 65536
#define D_IN  784
#define H1    400
#define H2    200
#define D_OUT 10

#define H1P   448   // H1 padded to multiple of 64 (7 waves per row)
#define H2P   256   // H2 padded to multiple of 64
#define W1W   25    // ceil(784/32) 32-bit mask words per w1 row
#define W3U   7     // ceil(448/64) u64 mask words per w3 row (j-dim padded)
#define W4U   4     // ceil(256/64) u64 mask words per w4 row

// ---------------------------------------------------------------- pack weights
__global__ __launch_bounds__(256) void pack_weights(
    const float* __restrict__ w1, const float* __restrict__ w3,
    const float* __restrict__ w4,
    uint32_t* __restrict__ neg1, uint32_t* __restrict__ nz1,
    uint64_t* __restrict__ neg3, uint64_t* __restrict__ nz3,
    uint64_t* __restrict__ neg4, uint64_t* __restrict__ nz4) {
  int t = blockIdx.x * 256 + threadIdx.x;
  if (t < H1 * W1W) {
    int n = t / W1W, w = t % W1W;
    uint32_t nm = 0, zm = 0;
    for (int k = 0; k < 32; ++k) {
      int i = w * 32 + k;
      if (i < D_IN) {
        float v = w1[n * D_IN + i];
        if (v != 0.0f) {
          zm |= (1u << k);
          if (v < 0.0f) nm |= (1u << k);
        }
      }
    }
    neg1[t] = nm;
    nz1[t] = zm;
  } else if (t < H1 * W1W + H2 * W3U) {
    int q = t - H1 * W1W;
    int m = q / W3U, w = q % W3U;
    uint64_t nm = 0, zm = 0;
    for (int k = 0; k < 64; ++k) {
      int j = w * 64 + k;
      if (j < H1) {
        float v = w3[m * H1 + j];
        if (v != 0.0f) {
          zm |= (1ull << k);
          if (v < 0.0f) nm |= (1ull << k);
        }
      }
    }
    neg3[q] = nm;
    nz3[q] = zm;
  } else if (t < H1 * W1W + H2 * W3U + D_OUT * W4U) {
    int q = t - H1 * W1W - H2 * W3U;
    int o = q / W4U, w = q % W4U;
    uint64_t nm = 0, zm = 0;
    for (int k = 0; k < 64; ++k) {
      int j = w * 64 + k;
      if (j < H2) {
        float v = w4[o * H2 + j];
        if (v != 0.0f) {
          zm |= (1ull << k);
          if (v < 0.0f) nm |= (1ull << k);
        }
      }
    }
    neg4[q] = nm;
    nz4[q] = zm;
  }
}

// ------------------------------------------------------------------- layer 1
// Bit-exact emulation of the SSE einsum f32 dot:
//   float32 v[4] = 0
//   for each 16-elem chunk (49 chunks, 784 = 49*16, no tail), ASCENDING:
//     lane j: v[j] += p[C+j]; += p[C+4+j]; += p[C+8+j]; += p[C+12+j]
//   r = (v0+v1) + (v2+v3)
// Products are exactly +/-x_i, so mul+add vs FMA is irrelevant; only the
// add tree matters. One thread per (b, n); lanes of a wave share b.
__global__ __launch_bounds__(256) void layer1_np(
    const float* __restrict__ x, const uint32_t* __restrict__ neg1,
    const uint32_t* __restrict__ nz1, uint64_t* __restrict__ s1neg,
    uint64_t* __restrict__ s1nz) {
  uint32_t idx = blockIdx.x * 256u + threadIdx.x;
  uint32_t b = idx / H1P;
  uint32_t n = idx - b * H1P;
  float r = 0.0f;
  if (n < H1) {
    const float* xr = x + (size_t)b * D_IN;
    const uint32_t* nmr = neg1 + n * W1W;
    const uint32_t* zmr = nz1 + n * W1W;
    float v0 = 0.0f, v1 = 0.0f, v2 = 0.0f, v3 = 0.0f;
    for (int c = 0; c < 49; ++c) {
      const float4* x4 = (const float4*)(xr + c * 16);
      float4 q0 = x4[0];
      float4 q1 = x4[1];
      float4 q2 = x4[2];
      float4 q3 = x4[3];
      uint32_t wrd = nmr[c >> 1];
      uint32_t zrd = zmr[c >> 1];
      uint32_t nm = (c & 1) ? (wrd >> 16) : (wrd & 0xffffu);
      uint32_t zm = (c & 1) ? (zrd >> 16) : (zrd & 0xffffu);
      // product term: w==0 -> +/-0 masked to +0; adding it never changes a
      // nonzero acc and matches numpy's +/-0 product at acc==0 sign-wise.
#define SGN(Q, K)                                                   \
  __uint_as_float((__float_as_uint(Q) ^ (((nm >> (K)) & 1u) << 31)) \
                  & (0u - ((zm >> (K)) & 1u)))
      // ASCENDING chain: elements 0..3 first, then 4..7, 8..11, 12..15
      v0 += SGN(q0.x, 0);  v1 += SGN(q0.y, 1);  v2 += SGN(q0.z, 2);  v3 += SGN(q0.w, 3);
      v0 += SGN(q1.x, 4);  v1 += SGN(q1.y, 5);  v2 += SGN(q1.z, 6);  v3 += SGN(q1.w, 7);
      v0 += SGN(q2.x, 8);  v1 += SGN(q2.y, 9);  v2 += SGN(q2.z, 10); v3 += SGN(q2.w, 11);
      v0 += SGN(q3.x, 12); v1 += SGN(q3.y, 13); v2 += SGN(q3.z, 14); v3 += SGN(q3.w, 15);
#undef SGN
    }
    r = (v0 + v1) + (v2 + v3);  // hadd-pairing horizontal sum
  }
  // sign(-0.0) = 0 handled: (-0 < 0) false, (-0 != 0) false
  uint64_t bneg = __ballot(r < 0.0f);
  uint64_t bnz = __ballot(r != 0.0f);
  if ((threadIdx.x & 63u) == 0u) {
    uint32_t widx = b * (H1P / 64) + (n >> 6);
    s1neg[widx] = bneg;
    s1nz[widx] = bnz;
  }
}

// ------------------------------------------------------------------- layer 2
// Exact integer dot of {-1,0,1} vectors via bit-planes:
// acc = popc(valid) - 2*popc(diff), valid = nzA & nzW, diff = (negA^negW)&valid
__global__ __launch_bounds__(256) void layer2(
    const uint64_t* __restrict__ s1neg, const uint64_t* __restrict__ s1nz,
    const uint64_t* __restrict__ neg3, const uint64_t* __restrict__ nz3,
    uint64_t* __restrict__ s2neg, uint64_t* __restrict__ s2nz) {
  uint32_t idx = blockIdx.x * 256u + threadIdx.x;
  uint32_t b = idx / H2P;
  uint32_t m = idx - b * H2P;
  int acc = 0;
  if (m < H2) {
    const uint64_t* an = s1neg + (size_t)b * (H1P / 64);
    const uint64_t* az = s1nz + (size_t)b * (H1P / 64);
    const uint64_t* wn = neg3 + m * W3U;
    const uint64_t* wz = nz3 + m * W3U;
#pragma unroll
    for (int w = 0; w < W3U; ++w) {
      uint64_t valid = az[w] & wz[w];
      uint64_t diff = (an[w] ^ wn[w]) & valid;
      acc += __popcll(valid) - 2 * __popcll(diff);
    }
  }
  uint64_t bneg = __ballot(acc < 0);
  uint64_t bnz = __ballot(acc != 0);
  if ((threadIdx.x & 63u) == 0u) {
    uint32_t widx = b * (H2P / 64) + (m >> 6);
    s2neg[widx] = bneg;
    s2nz[widx] = bnz;
  }
}

// ------------------------------------------------------------------- layer 3
__global__ __launch_bounds__(256) void layer3(
    const uint64_t* __restrict__ s2neg, const uint64_t* __restrict__ s2nz,
    const uint64_t* __restrict__ neg4, const uint64_t* __restrict__ nz4,
    float* __restrict__ out) {
  uint32_t idx = blockIdx.x * 256u + threadIdx.x;
  uint32_t b = idx >> 4;
  uint32_t o = idx & 15u;
  if (o < D_OUT) {
    const uint64_t* an = s2neg + (size_t)b * W4U;
    const uint64_t* az = s2nz + (size_t)b * W4U;
    const uint64_t* wn = neg4 + o * W4U;
    const uint64_t* wz = nz4 + o * W4U;
    int acc = 0;
#pragma unroll
    for (int w = 0; w < W4U; ++w) {
      uint64_t valid = az[w] & wz[w];
      uint64_t diff = (an[w] ^ wn[w]) & valid;
      acc += __popcll(valid) - 2 * __popcll(diff);
    }
    out[(size_t)b * D_OUT + o] = (float)acc;
  }
}

// -------------------------------------------------------------------- launch
extern "C" void kernel_launch(void* const* d_in, const int* in_sizes, int n_in,
                              void* d_out, int out_size, void* d_ws,
                              size_t ws_size, hipStream_t stream) {
  const float* x = (const float*)d_in[0];
  const float* w1 = (const float*)d_in[1];
  const float* w3 = (const float*)d_in[2];
  const float* w4 = (const float*)d_in[3];
  float* out = (float*)d_out;

  char* p = (char*)d_ws;
  uint32_t* neg1 = (uint32_t*)p;  p += (size_t)H1 * W1W * 4;
  uint32_t* nz1 = (uint32_t*)p;   p += (size_t)H1 * W1W * 4;
  uint64_t* neg3 = (uint64_t*)p;  p += (size_t)H2 * W3U * 8;
  uint64_t* nz3 = (uint64_t*)p;   p += (size_t)H2 * W3U * 8;
  uint64_t* neg4 = (uint64_t*)p;  p += (size_t)D_OUT * W4U * 8;
  uint64_t* nz4 = (uint64_t*)p;   p += (size_t)D_OUT * W4U * 8;
  uint64_t* s1neg = (uint64_t*)p; p += (size_t)BATCH * (H1P / 64) * 8;
  uint64_t* s1nz = (uint64_t*)p;  p += (size_t)BATCH * (H1P / 64) * 8;
  uint64_t* s2neg = (uint64_t*)p; p += (size_t)BATCH * (H2P / 64) * 8;
  uint64_t* s2nz = (uint64_t*)p;  p += (size_t)BATCH * (H2P / 64) * 8;

  hipLaunchKernelGGL(pack_weights, dim3(45), dim3(256), 0, stream, w1, w3, w4,
                     neg1, nz1, neg3, nz3, neg4, nz4);
  hipLaunchKernelGGL(layer1_np, dim3((BATCH * (H1P / 64) * 64) / 256),
                     dim3(256), 0, stream, x, neg1, nz1, s1neg, s1nz);
  hipLaunchKernelGGL(layer2, dim3((BATCH * H2P) / 256), dim3(256), 0, stream,
                     s1neg, s1nz, neg3, nz3, s2neg, s2nz);
  hipLaunchKernelGGL(layer3, dim3((BATCH * 16) / 256), dim3(256), 0, stream,
                     s2neg, s2nz, neg4, nz4, out);
}

// Round 11
// 1076.809 us; speedup vs baseline: 7.0595x; 7.0595x over previous
//
#include <hip/hip_runtime.h>
#include <stdint.h>

// Binarized MLP, fast path + exact fixup.
// Layer 1: bf16 hi/lo split MFMA GEMM (fast, approximate) computes C ~= dot.
// |C| >= TAU  ==> sign(C) == sign(exact np tree)   [rigorous error bound ~0.10]
// |C| <  TAU  ==> suspect: recompute with the bit-exact np tree (verified in
// round 10: chunk-16 SSE partition, ascending, hadd pairing) and patch bits.
// Layers 2/3: exact small-integer popcount arithmetic (order-independent).

#define BATCH 65536
#define D_IN  784
#define H1    400
#define H2    200
#define D_OUT 10

#define H1P   448
#define H2P   256
#define W1W   25
#define W3U   7
#define W4U   4

#define KP    800      // K padded to multiple of 32
#define LDA   808      // LDS A row stride (elems) -> 2-way-max bank aliasing
#define BM    32       // block M tile
#define GT    896      // gemm threads = 14 waves (2M x 7N of 16x64)
#define TAU   0.5f
#define SCAP  (1u << 21)

typedef __attribute__((ext_vector_type(8))) short short8;
typedef __attribute__((ext_vector_type(4))) float f32x4;

static __device__ __forceinline__ ushort f32_to_bf16_rne(float f) {
  uint32_t u = __float_as_uint(f);
  uint32_t r = (u + 0x7FFFu + ((u >> 16) & 1u)) >> 16;
  return (ushort)r;
}

// ---------------------------------------------------------------- pack weights
// masks for fixup/layer2/3 + Bt bf16 sign matrix [H1P][KP] (zero padded)
__global__ __launch_bounds__(256) void pack_weights(
    const float* __restrict__ w1, const float* __restrict__ w3,
    const float* __restrict__ w4,
    uint32_t* __restrict__ neg1, uint32_t* __restrict__ nz1,
    uint64_t* __restrict__ neg3, uint64_t* __restrict__ nz3,
    uint64_t* __restrict__ neg4, uint64_t* __restrict__ nz4,
    ushort* __restrict__ Bt) {
  int t = blockIdx.x * 256 + threadIdx.x;
  if (t < H1 * W1W) {
    int n = t / W1W, w = t % W1W;
    uint32_t nm = 0, zm = 0;
    for (int k = 0; k < 32; ++k) {
      int i = w * 32 + k;
      if (i < D_IN) {
        float v = w1[n * D_IN + i];
        if (v != 0.0f) {
          zm |= (1u << k);
          if (v < 0.0f) nm |= (1u << k);
        }
      }
    }
    neg1[t] = nm;
    nz1[t] = zm;
  } else if (t < H1 * W1W + H2 * W3U) {
    int q = t - H1 * W1W;
    int m = q / W3U, w = q % W3U;
    uint64_t nm = 0, zm = 0;
    for (int k = 0; k < 64; ++k) {
      int j = w * 64 + k;
      if (j < H1) {
        float v = w3[m * H1 + j];
        if (v != 0.0f) {
          zm |= (1ull << k);
          if (v < 0.0f) nm |= (1ull << k);
        }
      }
    }
    neg3[q] = nm;
    nz3[q] = zm;
  } else if (t < H1 * W1W + H2 * W3U + D_OUT * W4U) {
    int q = t - H1 * W1W - H2 * W3U;
    int o = q / W4U, w = q % W4U;
    uint64_t nm = 0, zm = 0;
    for (int k = 0; k < 64; ++k) {
      int j = w * 64 + k;
      if (j < H2) {
        float v = w4[o * H2 + j];
        if (v != 0.0f) {
          zm |= (1ull << k);
          if (v < 0.0f) nm |= (1ull << k);
        }
      }
    }
    neg4[q] = nm;
    nz4[q] = zm;
  } else if (t < H1 * W1W + H2 * W3U + D_OUT * W4U + H1P * KP) {
    int q = t - (H1 * W1W + H2 * W3U + D_OUT * W4U);
    int n = q / KP, k = q - n * KP;
    ushort b = 0;
    if (n < H1 && k < D_IN) {
      float v = w1[n * D_IN + k];
      b = (v > 0.0f) ? 0x3F80u : ((v < 0.0f) ? 0xBF80u : 0u);
    }
    Bt[q] = b;
  }
}

// ------------------------------------------------------------------- layer 1
// GEMM fast path: C[b][n] = x_row . sign(w1_row_n), bf16 hi/lo split, MFMA
// 16x16x32. Epilogue: bitplane signs via ballot (C layout: col=lane&15,
// row=(lane>>4)*4+reg), suspects (|C|<TAU, n<H1) compacted to a list.
__global__ __launch_bounds__(GT) void gemm_l1(
    const float* __restrict__ x, const ushort* __restrict__ Bt,
    uint64_t* __restrict__ s1neg, uint64_t* __restrict__ s1nz,
    uint32_t* __restrict__ slist, uint32_t* __restrict__ scount) {
  __shared__ __align__(16) ushort Ah[BM * LDA];
  __shared__ __align__(16) ushort Al[BM * LDA];
  const uint32_t tid = threadIdx.x;
  const uint32_t b0 = blockIdx.x * BM;

  // stage A (f32 -> bf16 hi/lo) into LDS, K zero-padded to KP
  for (uint32_t i = tid; i < BM * KP; i += GT) {
    uint32_t r = i / KP, k = i - r * KP;
    float v = (k < D_IN) ? x[(size_t)(b0 + r) * D_IN + k] : 0.0f;
    ushort hi = f32_to_bf16_rne(v);
    float hif = __uint_as_float((uint32_t)hi << 16);
    ushort lo = f32_to_bf16_rne(v - hif);
    Ah[r * LDA + k] = hi;
    Al[r * LDA + k] = lo;
  }
  __syncthreads();

  const uint32_t wave = tid >> 6, lane = tid & 63;
  const uint32_t wm = wave & 1, wn = wave >> 1;  // wn = 0..6 (n-word index)
  const uint32_t row16 = lane & 15, oct = lane >> 4;
  const uint32_t m_base = wm * 16, n_base = wn * 64;

  f32x4 acc[4];
  acc[0] = (f32x4){0.f, 0.f, 0.f, 0.f};
  acc[1] = (f32x4){0.f, 0.f, 0.f, 0.f};
  acc[2] = (f32x4){0.f, 0.f, 0.f, 0.f};
  acc[3] = (f32x4){0.f, 0.f, 0.f, 0.f};

  const ushort* ah_base = &Ah[(m_base + row16) * LDA];
  const ushort* al_base = &Al[(m_base + row16) * LDA];
  for (int j = 0; j < 25; ++j) {
    uint32_t k0 = j * 32 + oct * 8;
    short8 ah = *(const short8*)(ah_base + k0);
    short8 al = *(const short8*)(al_base + k0);
#pragma unroll
    for (int nf = 0; nf < 4; ++nf) {
      short8 bb = *(const short8*)(Bt + (size_t)(n_base + nf * 16 + row16) * KP + k0);
      acc[nf] = __builtin_amdgcn_mfma_f32_16x16x32_bf16(ah, bb, acc[nf], 0, 0, 0);
      acc[nf] = __builtin_amdgcn_mfma_f32_16x16x32_bf16(al, bb, acc[nf], 0, 0, 0);
    }
  }

  // epilogue: bitplanes + suspect mask
  uint32_t smask = 0;
#pragma unroll
  for (int q = 0; q < 4; ++q) {
    uint64_t bn[4], bz[4];
#pragma unroll
    for (int nf = 0; nf < 4; ++nf) {
      float c = acc[nf][q];
      uint32_t nabs = n_base + nf * 16 + row16;
      bn[nf] = __ballot(c < 0.0f);
      bz[nf] = __ballot(c != 0.0f);
      if (fabsf(c) < TAU && nabs < H1) smask |= 1u << (q * 4 + nf);
    }
    if (row16 == (uint32_t)q) {
      uint64_t wneg = 0, wnz = 0;
#pragma unroll
      for (int nf = 0; nf < 4; ++nf) {
        wneg |= ((bn[nf] >> (16 * oct)) & 0xFFFFull) << (16 * nf);
        wnz |= ((bz[nf] >> (16 * oct)) & 0xFFFFull) << (16 * nf);
      }
      uint32_t row = b0 + m_base + oct * 4 + q;
      s1neg[(size_t)row * W3U + wn] = wneg;
      s1nz[(size_t)row * W3U + wn] = wnz;
    }
  }

  // wave-aggregated suspect compaction (one atomic per wave)
  int scnt = __popc(smask);
  int pre = scnt;
  for (int d = 1; d < 64; d <<= 1) {
    int t = __shfl_up(pre, d);
    if ((int)lane >= d) pre += t;
  }
  int total = __shfl(pre, 63);
  if (total > 0) {
    uint32_t base = 0;
    if (lane == 63) base = atomicAdd(scount, (uint32_t)total);
    base = (uint32_t)__shfl((int)base, 63);
    uint32_t idx = base + (uint32_t)(pre - scnt);
#pragma unroll
    for (int q = 0; q < 4; ++q)
#pragma unroll
      for (int nf = 0; nf < 4; ++nf)
        if ((smask >> (q * 4 + nf)) & 1u) {
          uint32_t nabs = n_base + nf * 16 + row16;
          uint32_t row = b0 + m_base + oct * 4 + q;
          if (idx < SCAP) slist[idx] = (row << 9) | nabs;
          ++idx;
        }
  }
}

// --------------------------------------------------------------------- fixup
// Recompute suspects with the bit-exact np tree (round-10 verified) and patch
// the s1 bitplanes atomically.
__global__ __launch_bounds__(256) void fixup(
    const float* __restrict__ x, const uint32_t* __restrict__ neg1,
    const uint32_t* __restrict__ nz1, const uint32_t* __restrict__ slist,
    const uint32_t* __restrict__ scount, uint64_t* __restrict__ s1neg,
    uint64_t* __restrict__ s1nz) {
  uint32_t cnt = *scount;
  if (cnt > SCAP) cnt = SCAP;
  uint32_t i = blockIdx.x * 256 + threadIdx.x;
  if (i >= cnt) return;
  uint32_t val = slist[i];
  uint32_t b = val >> 9, n = val & 511u;
  const float* xr = x + (size_t)b * D_IN;
  const uint32_t* nmr = neg1 + n * W1W;
  const uint32_t* zmr = nz1 + n * W1W;
  float v0 = 0.0f, v1 = 0.0f, v2 = 0.0f, v3 = 0.0f;
  for (int c = 0; c < 49; ++c) {
    const float4* x4 = (const float4*)(xr + c * 16);
    float4 q0 = x4[0];
    float4 q1 = x4[1];
    float4 q2 = x4[2];
    float4 q3 = x4[3];
    uint32_t wrd = nmr[c >> 1];
    uint32_t zrd = zmr[c >> 1];
    uint32_t nm = (c & 1) ? (wrd >> 16) : (wrd & 0xffffu);
    uint32_t zm = (c & 1) ? (zrd >> 16) : (zrd & 0xffffu);
#define SGN(Q, K)                                                   \
  __uint_as_float((__float_as_uint(Q) ^ (((nm >> (K)) & 1u) << 31)) \
                  & (0u - ((zm >> (K)) & 1u)))
    v0 += SGN(q0.x, 0);  v1 += SGN(q0.y, 1);  v2 += SGN(q0.z, 2);  v3 += SGN(q0.w, 3);
    v0 += SGN(q1.x, 4);  v1 += SGN(q1.y, 5);  v2 += SGN(q1.z, 6);  v3 += SGN(q1.w, 7);
    v0 += SGN(q2.x, 8);  v1 += SGN(q2.y, 9);  v2 += SGN(q2.z, 10); v3 += SGN(q2.w, 11);
    v0 += SGN(q3.x, 12); v1 += SGN(q3.y, 13); v2 += SGN(q3.z, 14); v3 += SGN(q3.w, 15);
#undef SGN
  }
  float r = (v0 + v1) + (v2 + v3);
  uint64_t mask = 1ull << (n & 63u);
  unsigned long long* pn = (unsigned long long*)&s1neg[(size_t)b * W3U + (n >> 6)];
  unsigned long long* pz = (unsigned long long*)&s1nz[(size_t)b * W3U + (n >> 6)];
  if (r < 0.0f) atomicOr(pn, mask); else atomicAnd(pn, ~mask);
  if (r != 0.0f) atomicOr(pz, mask); else atomicAnd(pz, ~mask);
}

// ------------------------------------------------------------------- layer 2
__global__ __launch_bounds__(256) void layer2(
    const uint64_t* __restrict__ s1neg, const uint64_t* __restrict__ s1nz,
    const uint64_t* __restrict__ neg3, const uint64_t* __restrict__ nz3,
    uint64_t* __restrict__ s2neg, uint64_t* __restrict__ s2nz) {
  uint32_t idx = blockIdx.x * 256u + threadIdx.x;
  uint32_t b = idx / H2P;
  uint32_t m = idx - b * H2P;
  int acc = 0;
  if (m < H2) {
    const uint64_t* an = s1neg + (size_t)b * W3U;
    const uint64_t* az = s1nz + (size_t)b * W3U;
    const uint64_t* wn = neg3 + m * W3U;
    const uint64_t* wz = nz3 + m * W3U;
#pragma unroll
    for (int w = 0; w < W3U; ++w) {
      uint64_t valid = az[w] & wz[w];
      uint64_t diff = (an[w] ^ wn[w]) & valid;
      acc += __popcll(valid) - 2 * __popcll(diff);
    }
  }
  uint64_t bneg = __ballot(acc < 0);
  uint64_t bnz = __ballot(acc != 0);
  if ((threadIdx.x & 63u) == 0u) {
    uint32_t widx = b * W4U + (m >> 6);
    s2neg[widx] = bneg;
    s2nz[widx] = bnz;
  }
}

// ------------------------------------------------------------------- layer 3
__global__ __launch_bounds__(256) void layer3(
    const uint64_t* __restrict__ s2neg, const uint64_t* __restrict__ s2nz,
    const uint64_t* __restrict__ neg4, const uint64_t* __restrict__ nz4,
    float* __restrict__ out) {
  uint32_t idx = blockIdx.x * 256u + threadIdx.x;
  uint32_t b = idx >> 4;
  uint32_t o = idx & 15u;
  if (o < D_OUT) {
    const uint64_t* an = s2neg + (size_t)b * W4U;
    const uint64_t* az = s2nz + (size_t)b * W4U;
    const uint64_t* wn = neg4 + o * W4U;
    const uint64_t* wz = nz4 + o * W4U;
    int acc = 0;
#pragma unroll
    for (int w = 0; w < W4U; ++w) {
      uint64_t valid = az[w] & wz[w];
      uint64_t diff = (an[w] ^ wn[w]) & valid;
      acc += __popcll(valid) - 2 * __popcll(diff);
    }
    out[(size_t)b * D_OUT + o] = (float)acc;
  }
}

// -------------------------------------------------------------------- launch
extern "C" void kernel_launch(void* const* d_in, const int* in_sizes, int n_in,
                              void* d_out, int out_size, void* d_ws,
                              size_t ws_size, hipStream_t stream) {
  const float* x = (const float*)d_in[0];
  const float* w1 = (const float*)d_in[1];
  const float* w3 = (const float*)d_in[2];
  const float* w4 = (const float*)d_in[3];
  float* out = (float*)d_out;

  char* p = (char*)d_ws;
  uint32_t* neg1 = (uint32_t*)p;  p += (size_t)H1 * W1W * 4;
  uint32_t* nz1 = (uint32_t*)p;   p += (size_t)H1 * W1W * 4;
  uint64_t* neg3 = (uint64_t*)p;  p += (size_t)H2 * W3U * 8;
  uint64_t* nz3 = (uint64_t*)p;   p += (size_t)H2 * W3U * 8;
  uint64_t* neg4 = (uint64_t*)p;  p += (size_t)D_OUT * W4U * 8;
  uint64_t* nz4 = (uint64_t*)p;   p += (size_t)D_OUT * W4U * 8;
  uint64_t* s1neg = (uint64_t*)p; p += (size_t)BATCH * W3U * 8;
  uint64_t* s1nz = (uint64_t*)p;  p += (size_t)BATCH * W3U * 8;
  uint64_t* s2neg = (uint64_t*)p; p += (size_t)BATCH * W4U * 8;
  uint64_t* s2nz = (uint64_t*)p;  p += (size_t)BATCH * W4U * 8;
  ushort* Bt = (ushort*)p;        p += (size_t)H1P * KP * 2;
  uint32_t* scount = (uint32_t*)p; p += 16;
  uint32_t* slist = (uint32_t*)p;  p += (size_t)SCAP * 4;
  // total ~20.3 MB

  hipMemsetAsync(scount, 0, 4, stream);

  int pack_jobs = H1 * W1W + H2 * W3U + D_OUT * W4U + H1P * KP;
  hipLaunchKernelGGL(pack_weights, dim3((pack_jobs + 255) / 256), dim3(256), 0,
                     stream, w1, w3, w4, neg1, nz1, neg3, nz3, neg4, nz4, Bt);
  hipLaunchKernelGGL(gemm_l1, dim3(BATCH / BM), dim3(GT), 0, stream, x, Bt,
                     s1neg, s1nz, slist, scount);
  hipLaunchKernelGGL(fixup, dim3(SCAP / 256), dim3(256), 0, stream, x, neg1,
                     nz1, slist, scount, s1neg, s1nz);
  hipLaunchKernelGGL(layer2, dim3((BATCH * H2P) / 256), dim3(256), 0, stream,
                     s1neg, s1nz, neg3, nz3, s2neg, s2nz);
  hipLaunchKernelGGL(layer3, dim3((BATCH * 16) / 256), dim3(256), 0, stream,
                     s2neg, s2nz, neg4, nz4, out);
}